// Round 1
// baseline (154.237 us; speedup 1.0000x reference)
//
#include <hip/hip_runtime.h>

#define WW 512
#define HH 256
#define TS 48
#define NB 2

#define KAPPA 0.01f
#define NU 0.01f

// jnp.gradient first+second (gradient-of-gradient) along one axis, at index i of n,
// given f at i-2,i-1,i,i+1,i+2 (clamped loads; out-of-range values unused).
__device__ __forceinline__ void grad12(float fm2, float fm1, float fc, float fp1, float fp2,
                                       int i, int n, float invh, float& g, float& gg) {
    const float half = 0.5f * invh;
    if (i == 0) {
        g = (fp1 - fc) * invh;                 // one-sided
        float g1 = (fp2 - fc) * half;          // central at i=1
        gg = (g1 - g) * invh;                  // one-sided on g
    } else if (i == n - 1) {
        g = (fc - fm1) * invh;
        float gm = (fc - fm2) * half;          // central at n-2
        gg = (g - gm) * invh;
    } else {
        g = (fp1 - fm1) * half;
        float gim = (i == 1)     ? (fc - fm1) * invh : (fc - fm2) * half;
        float gip = (i == n - 2) ? (fp1 - fc) * invh : (fp2 - fc) * half;
        gg = (gip - gim) * half;
    }
}

__device__ __forceinline__ float grad1(float fm1, float fc, float fp1, int i, int n, float invh) {
    if (i == 0)     return (fp1 - fc) * invh;
    if (i == n - 1) return (fc - fm1) * invh;
    return (fp1 - fm1) * (0.5f * invh);
}

__global__ __launch_bounds__(256) void rbc_loss_kernel(const float* __restrict__ pred,
                                                       double* __restrict__ dacc) {
    const int sT = HH * WW;          // 131072
    const int sC = TS * sT;          // 6291456
    const int sB = 5 * sC;

    const int gid = blockIdx.x * blockDim.x + threadIdx.x;   // 0 .. 2*256*512-1
    const int x = gid & (WW - 1);
    const int z = (gid >> 9) & (HH - 1);
    const int b = gid >> 17;

    const int xm1 = max(x - 1, 0), xm2 = max(x - 2, 0);
    const int xp1 = min(x + 1, WW - 1), xp2 = min(x + 2, WW - 1);
    const int zm1 = max(z - 1, 0), zm2 = max(z - 2, 0);
    const int zp1 = min(z + 1, HH - 1), zp2 = min(z + 2, HH - 1);

    const float invdt = 48.0f / 10.0f;
    const float invdx = (float)(512.0 / 6.283185307179586);
    const float invdz = 128.0f;

    const float* baseT  = pred + b * sB + 0 * sC;
    const float* baseU  = pred + b * sB + 1 * sC;
    const float* baseWc = pred + b * sB + 2 * sC;
    const float* baseP3 = pred + b * sB + 3 * sC;
    const float* baseP4 = pred + b * sB + 4 * sC;

    const int ctr = z * WW + x;

    // time ring buffers (center values)
    float Tp = 0.f, Tc = baseT[ctr],  Tn = 0.f;
    float Up = 0.f, Uc = baseU[ctr],  Un = 0.f;
    float Vp = 0.f, Vc = baseWc[ctr], Vn = 0.f;   // V == w-velocity

    float acc = 0.f;

    for (int t = 0; t < TS; ++t) {
        const int toff = t * sT;
        const float* pT = baseT  + toff;
        const float* pU = baseU  + toff;
        const float* pV = baseWc + toff;
        const float* p3 = baseP3 + toff;
        const float* p4 = baseP4 + toff;

        if (t < TS - 1) {
            const int noff = toff + sT + ctr;
            Tn = baseT[noff]; Un = baseU[noff]; Vn = baseWc[noff];
        }

        const int row = z * WW;
        // x-stencil
        float Txm2 = pT[row + xm2], Txm1 = pT[row + xm1], Txp1 = pT[row + xp1], Txp2 = pT[row + xp2];
        float Uxm2 = pU[row + xm2], Uxm1 = pU[row + xm1], Uxp1 = pU[row + xp1], Uxp2 = pU[row + xp2];
        float Vxm2 = pV[row + xm2], Vxm1 = pV[row + xm1], Vxp1 = pV[row + xp1], Vxp2 = pV[row + xp2];
        // z-stencil
        float Tzm2 = pT[zm2 * WW + x], Tzm1 = pT[zm1 * WW + x], Tzp1 = pT[zp1 * WW + x], Tzp2 = pT[zp2 * WW + x];
        float Uzm2 = pU[zm2 * WW + x], Uzm1 = pU[zm1 * WW + x], Uzp1 = pU[zp1 * WW + x], Uzp2 = pU[zp2 * WW + x];
        float Vzm2 = pV[zm2 * WW + x], Vzm1 = pV[zm1 * WW + x], Vzp1 = pV[zp1 * WW + x], Vzp2 = pV[zp2 * WW + x];
        // p = c3 + c4 (first derivatives only)
        float Pc   = p3[row + x]       + p4[row + x];
        float Pxm1 = p3[row + xm1]     + p4[row + xm1];
        float Pxp1 = p3[row + xp1]     + p4[row + xp1];
        float Pzm1 = p3[zm1 * WW + x]  + p4[zm1 * WW + x];
        float Pzp1 = p3[zp1 * WW + x]  + p4[zp1 * WW + x];

        float dTdx, dTdxx, dTdz, dTdzz;
        grad12(Txm2, Txm1, Tc, Txp1, Txp2, x, WW, invdx, dTdx, dTdxx);
        grad12(Tzm2, Tzm1, Tc, Tzp1, Tzp2, z, HH, invdz, dTdz, dTdzz);
        float dUdx, dUdxx, dUdz, dUdzz;
        grad12(Uxm2, Uxm1, Uc, Uxp1, Uxp2, x, WW, invdx, dUdx, dUdxx);
        grad12(Uzm2, Uzm1, Uc, Uzp1, Uzp2, z, HH, invdz, dUdz, dUdzz);
        float dVdx, dVdxx, dVdz, dVdzz;
        grad12(Vxm2, Vxm1, Vc, Vxp1, Vxp2, x, WW, invdx, dVdx, dVdxx);
        grad12(Vzm2, Vzm1, Vc, Vzp1, Vzp2, z, HH, invdz, dVdz, dVdzz);

        float dPdx = grad1(Pxm1, Pc, Pxp1, x, WW, invdx);
        float dPdz = grad1(Pzm1, Pc, Pzp1, z, HH, invdz);

        float dTdt = (t == 0) ? (Tn - Tc) * invdt
                   : (t == TS - 1) ? (Tc - Tp) * invdt
                   : (Tn - Tp) * (0.5f * invdt);
        float dUdt = (t == 0) ? (Un - Uc) * invdt
                   : (t == TS - 1) ? (Uc - Up) * invdt
                   : (Un - Up) * (0.5f * invdt);
        float dVdt = (t == 0) ? (Vn - Vc) * invdt
                   : (t == TS - 1) ? (Vc - Vp) * invdt
                   : (Vn - Vp) * (0.5f * invdt);

        float div = dUdx + dVdz;
        float te  = dTdt + Uc * dTdx + Vc * dTdz - KAPPA * (dTdxx + dTdzz);
        float xm  = dUdt + Uc * dUdx + Vc * dUdz + dPdx - NU * (dUdxx + dUdzz);
        float zm  = dVdt + Uc * dVdx + Vc * dVdz + dPdz - NU * (dVdxx + dVdzz) - Tc;

        acc += div * div + te * te + xm * xm + zm * zm;

        Tp = Tc; Tc = Tn;
        Up = Uc; Uc = Un;
        Vp = Vc; Vc = Vn;
    }

    // block reduction: wave shfl -> LDS -> one double atomic per block
    #pragma unroll
    for (int off = 32; off; off >>= 1) acc += __shfl_down(acc, off, 64);
    __shared__ float wsum[4];
    const int lane = threadIdx.x & 63, wid = threadIdx.x >> 6;
    if (lane == 0) wsum[wid] = acc;
    __syncthreads();
    if (threadIdx.x == 0) {
        float s = wsum[0] + wsum[1] + wsum[2] + wsum[3];
        atomicAdd(dacc, (double)s);
    }
}

__global__ void rbc_finalize(const double* __restrict__ dacc, float* __restrict__ out) {
    const double N = (double)NB * TS * HH * WW;   // 12,582,912
    out[0] = (float)(dacc[0] / N);
}

extern "C" void kernel_launch(void* const* d_in, const int* in_sizes, int n_in,
                              void* d_out, int out_size, void* d_ws, size_t ws_size,
                              hipStream_t stream) {
    const float* pred = (const float*)d_in[0];
    double* dacc = (double*)d_ws;
    hipMemsetAsync(dacc, 0, sizeof(double), stream);

    const int total = NB * HH * WW;            // 262,144 threads, one per (b,z,x)
    rbc_loss_kernel<<<total / 256, 256, 0, stream>>>(pred, dacc);
    rbc_finalize<<<1, 1, 0, stream>>>(dacc, (float*)d_out);
}

// Round 2
// 105.707 us; speedup vs baseline: 1.4591x; 1.4591x over previous
//
#include <hip/hip_runtime.h>

#define WW 512
#define HH 256
#define TS 48
#define NB 2
#define ZS 64          // z-strip height per block
#define NSTRIP 4       // HH / ZS
#define KAPPA 0.01f
#define NU 0.01f

// clamped row byte-offset helper
#define ROW(zz) (min(max((zz), 0), HH - 1) * WW)

// jnp.gradient first+second (gradient-of-gradient) along one axis, at index i of n.
__device__ __forceinline__ void grad12(float fm2, float fm1, float fc, float fp1, float fp2,
                                       int i, int n, float invh, float& g, float& gg) {
    const float half = 0.5f * invh;
    if (i == 0) {
        g = (fp1 - fc) * invh;
        float g1 = (fp2 - fc) * half;
        gg = (g1 - g) * invh;
    } else if (i == n - 1) {
        g = (fc - fm1) * invh;
        float gm = (fc - fm2) * half;
        gg = (g - gm) * invh;
    } else {
        g = (fp1 - fm1) * half;
        float gim = (i == 1)     ? (fc - fm1) * invh : (fc - fm2) * half;
        float gip = (i == n - 2) ? (fp1 - fc) * invh : (fp2 - fc) * half;
        gg = (gip - gim) * half;
    }
}

__device__ __forceinline__ float grad1(float fm1, float fc, float fp1, int i, int n, float invh) {
    if (i == 0)     return (fp1 - fc) * invh;
    if (i == n - 1) return (fc - fm1) * invh;
    return (fp1 - fm1) * (0.5f * invh);
}

__global__ __launch_bounds__(256) void rbc_loss_kernel(const float* __restrict__ pred,
                                                       double* __restrict__ dacc) {
    const int sT = HH * WW;          // 131072
    const int sC = TS * sT;          // 6291456
    const int sB = 5 * sC;

    // XCD-chunked swizzle: hw block i -> logical n. 768 % 8 == 0 -> bijective.
    // Each XCD gets 96 consecutive logical blocks = 12 consecutive t values,
    // so the t+-1 plane reads of neighboring t-blocks share the same L2.
    const int bi = blockIdx.x;
    const int n  = (bi & 7) * (gridDim.x >> 3) + (bi >> 3);

    // logical n = ((b*TS + t)*2 + xh)*NSTRIP + s
    const int s  = n & (NSTRIP - 1);
    const int xh = (n >> 2) & 1;
    const int t  = (n >> 3) % TS;
    const int b  = n / (8 * TS);

    const int x  = (xh << 8) + threadIdx.x;   // 0..511
    const int z0 = s * ZS;

    const int xm1 = max(x - 1, 0), xm2 = max(x - 2, 0);
    const int xp1 = min(x + 1, WW - 1), xp2 = min(x + 2, WW - 1);

    const float invdt = TS / 10.0f;                       // 4.8
    const float invdx = (float)(WW / 6.283185307179586);  // 81.487...
    const float invdz = HH / 2.0f;                        // 128

    const float* __restrict__ pT = pred + b * sB + 0 * sC + t * sT;
    const float* __restrict__ pU = pred + b * sB + 1 * sC + t * sT;
    const float* __restrict__ pV = pred + b * sB + 2 * sC + t * sT;
    const float* __restrict__ q3 = pred + b * sB + 3 * sC + t * sT;
    const float* __restrict__ q4 = pred + b * sB + 4 * sC + t * sT;
    const float* __restrict__ pTm = (t > 0)      ? pT - sT : pT;
    const float* __restrict__ pTp = (t < TS - 1) ? pT + sT : pT;
    const float* __restrict__ pUm = (t > 0)      ? pU - sT : pU;
    const float* __restrict__ pUp = (t < TS - 1) ? pU + sT : pU;
    const float* __restrict__ pVm = (t > 0)      ? pV - sT : pV;
    const float* __restrict__ pVp = (t < TS - 1) ? pV + sT : pV;

    // z-ring warm-up (clamped rows; clamped values are exactly what the edge
    // branches of grad12 need, and unused slots don't affect results)
    float Tzm2 = pT[ROW(z0 - 2) + x], Tzm1 = pT[ROW(z0 - 1) + x];
    float Tzc  = pT[ROW(z0)     + x], Tzp1 = pT[ROW(z0 + 1) + x];
    float Uzm2 = pU[ROW(z0 - 2) + x], Uzm1 = pU[ROW(z0 - 1) + x];
    float Uzc  = pU[ROW(z0)     + x], Uzp1 = pU[ROW(z0 + 1) + x];
    float Vzm2 = pV[ROW(z0 - 2) + x], Vzm1 = pV[ROW(z0 - 1) + x];
    float Vzc  = pV[ROW(z0)     + x], Vzp1 = pV[ROW(z0 + 1) + x];
    float Pzm1 = q3[ROW(z0 - 1) + x] + q4[ROW(z0 - 1) + x];
    float Pzc  = q3[ROW(z0)     + x] + q4[ROW(z0)     + x];

    float acc = 0.f;

    for (int z = z0; z < z0 + ZS; ++z) {
        const int rC = z * WW;
        const int rP2 = ROW(z + 2);
        const int rP1 = ROW(z + 1);

        // ring advance loads (unique-streamed)
        float Tzp2 = pT[rP2 + x];
        float Uzp2 = pU[rP2 + x];
        float Vzp2 = pV[rP2 + x];
        float Pzp1 = q3[rP1 + x] + q4[rP1 + x];

        // x-stencil at center row (L1-resident: fetched 2 iters ago)
        float Txm2 = pT[rC + xm2], Txm1 = pT[rC + xm1], Txp1 = pT[rC + xp1], Txp2 = pT[rC + xp2];
        float Uxm2 = pU[rC + xm2], Uxm1 = pU[rC + xm1], Uxp1 = pU[rC + xp1], Uxp2 = pU[rC + xp2];
        float Vxm2 = pV[rC + xm2], Vxm1 = pV[rC + xm1], Vxp1 = pV[rC + xp1], Vxp2 = pV[rC + xp2];
        float Pxm1 = q3[rC + xm1] + q4[rC + xm1];
        float Pxp1 = q3[rC + xp1] + q4[rC + xp1];

        // t-neighbors at center (shared with t+-1 blocks via same-XCD L2)
        float Ttm = pTm[rC + x], Ttp = pTp[rC + x];
        float Utm = pUm[rC + x], Utp = pUp[rC + x];
        float Vtm = pVm[rC + x], Vtp = pVp[rC + x];

        float dTdx, dTdxx, dTdz, dTdzz;
        grad12(Txm2, Txm1, Tzc, Txp1, Txp2, x, WW, invdx, dTdx, dTdxx);
        grad12(Tzm2, Tzm1, Tzc, Tzp1, Tzp2, z, HH, invdz, dTdz, dTdzz);
        float dUdx, dUdxx, dUdz, dUdzz;
        grad12(Uxm2, Uxm1, Uzc, Uxp1, Uxp2, x, WW, invdx, dUdx, dUdxx);
        grad12(Uzm2, Uzm1, Uzc, Uzp1, Uzp2, z, HH, invdz, dUdz, dUdzz);
        float dVdx, dVdxx, dVdz, dVdzz;
        grad12(Vxm2, Vxm1, Vzc, Vxp1, Vxp2, x, WW, invdx, dVdx, dVdxx);
        grad12(Vzm2, Vzm1, Vzc, Vzp1, Vzp2, z, HH, invdz, dVdz, dVdzz);

        float dPdx = grad1(Pxm1, Pzc, Pxp1, x, WW, invdx);
        float dPdz = grad1(Pzm1, Pzc, Pzp1, z, HH, invdz);

        // t is block-uniform -> no divergence
        float dTdt, dUdt, dVdt;
        if (t == 0) {
            dTdt = (Ttp - Tzc) * invdt;
            dUdt = (Utp - Uzc) * invdt;
            dVdt = (Vtp - Vzc) * invdt;
        } else if (t == TS - 1) {
            dTdt = (Tzc - Ttm) * invdt;
            dUdt = (Uzc - Utm) * invdt;
            dVdt = (Vzc - Vtm) * invdt;
        } else {
            dTdt = (Ttp - Ttm) * (0.5f * invdt);
            dUdt = (Utp - Utm) * (0.5f * invdt);
            dVdt = (Vtp - Vtm) * (0.5f * invdt);
        }

        float div = dUdx + dVdz;
        float te  = dTdt + Uzc * dTdx + Vzc * dTdz - KAPPA * (dTdxx + dTdzz);
        float xm  = dUdt + Uzc * dUdx + Vzc * dUdz + dPdx - NU * (dUdxx + dUdzz);
        float zm  = dVdt + Uzc * dVdx + Vzc * dVdz + dPdz - NU * (dVdxx + dVdzz) - Tzc;

        acc += div * div + te * te + xm * xm + zm * zm;

        // shift rings
        Tzm2 = Tzm1; Tzm1 = Tzc; Tzc = Tzp1; Tzp1 = Tzp2;
        Uzm2 = Uzm1; Uzm1 = Uzc; Uzc = Uzp1; Uzp1 = Uzp2;
        Vzm2 = Vzm1; Vzm1 = Vzc; Vzc = Vzp1; Vzp1 = Vzp2;
        Pzm1 = Pzc;  Pzc  = Pzp1;
    }

    // block reduction: wave shfl -> LDS -> one double atomic per block
    #pragma unroll
    for (int off = 32; off; off >>= 1) acc += __shfl_down(acc, off, 64);
    __shared__ float wsum[4];
    const int lane = threadIdx.x & 63, wid = threadIdx.x >> 6;
    if (lane == 0) wsum[wid] = acc;
    __syncthreads();
    if (threadIdx.x == 0) {
        float ssum = wsum[0] + wsum[1] + wsum[2] + wsum[3];
        atomicAdd(dacc, (double)ssum);
    }
}

__global__ void rbc_finalize(const double* __restrict__ dacc, float* __restrict__ out) {
    const double N = (double)NB * TS * HH * WW;   // 12,582,912
    out[0] = (float)(dacc[0] / N);
}

extern "C" void kernel_launch(void* const* d_in, const int* in_sizes, int n_in,
                              void* d_out, int out_size, void* d_ws, size_t ws_size,
                              hipStream_t stream) {
    const float* pred = (const float*)d_in[0];
    double* dacc = (double*)d_ws;
    hipMemsetAsync(dacc, 0, sizeof(double), stream);

    const int nblocks = NB * TS * 2 * NSTRIP;   // 768 = 3 blocks/CU exactly
    rbc_loss_kernel<<<nblocks, 256, 0, stream>>>(pred, dacc);
    rbc_finalize<<<1, 1, 0, stream>>>(dacc, (float*)d_out);
}

// Round 3
// 95.009 us; speedup vs baseline: 1.6234x; 1.1126x over previous
//
#include <hip/hip_runtime.h>

#define WW 512
#define HH 256
#define TS 48
#define NB 2
#define ZS 16          // z-strip height per block
#define NSTRIP 16      // HH / ZS
#define KAPPA 0.01f
#define NU 0.01f

#define ROW(zz) (min(max((zz), 0), HH - 1) * WW)
#define LD4(p) (*reinterpret_cast<const float4*>(p))

__device__ __forceinline__ float elem(const float4 v, int e) {
    return e == 0 ? v.x : e == 1 ? v.y : e == 2 ? v.z : v.w;
}

// jnp.gradient first+second (gradient-of-gradient) along one axis, index i of n.
__device__ __forceinline__ void grad12(float fm2, float fm1, float fc, float fp1, float fp2,
                                       int i, int n, float invh, float& g, float& gg) {
    const float half = 0.5f * invh;
    if (i == 0) {
        g = (fp1 - fc) * invh;
        float g1 = (fp2 - fc) * half;
        gg = (g1 - g) * invh;
    } else if (i == n - 1) {
        g = (fc - fm1) * invh;
        float gm = (fc - fm2) * half;
        gg = (g - gm) * invh;
    } else {
        g = (fp1 - fm1) * half;
        float gim = (i == 1)     ? (fc - fm1) * invh : (fc - fm2) * half;
        float gip = (i == n - 2) ? (fp1 - fc) * invh : (fp2 - fc) * half;
        gg = (gip - gim) * half;
    }
}

__device__ __forceinline__ float grad1(float fm1, float fc, float fp1, int i, int n, float invh) {
    if (i == 0)     return (fp1 - fc) * invh;
    if (i == n - 1) return (fc - fm1) * invh;
    return (fp1 - fm1) * (0.5f * invh);
}

__global__ __launch_bounds__(128) void rbc_loss_kernel(const float* __restrict__ pred,
                                                       double* __restrict__ dacc) {
    const int sT = HH * WW;          // 131072
    const int sC = TS * sT;          // 6291456
    const int sB = 5 * sC;

    // XCD-chunked swizzle (1536 % 8 == 0 -> bijective). 192 logical blocks per
    // XCD = 12 consecutive t values -> t+-1 plane reads are same-L2.
    const int bi = blockIdx.x;
    const int n  = (bi & 7) * (gridDim.x >> 3) + (bi >> 3);

    // logical n = (b*TS + t)*NSTRIP + s
    const int s = n & (NSTRIP - 1);
    const int t = (n >> 4) % TS;
    const int b = n / (NSTRIP * TS);

    const int x0 = threadIdx.x << 2;   // 0..508, quad base
    const int z0 = s * ZS;

    const float invdt = TS / 10.0f;
    const float invdx = (float)(WW / 6.283185307179586);
    const float invdz = HH / 2.0f;

    const float* __restrict__ pT = pred + b * sB + 0 * sC + t * sT;
    const float* __restrict__ pU = pred + b * sB + 1 * sC + t * sT;
    const float* __restrict__ pV = pred + b * sB + 2 * sC + t * sT;
    const float* __restrict__ q3 = pred + b * sB + 3 * sC + t * sT;
    const float* __restrict__ q4 = pred + b * sB + 4 * sC + t * sT;
    const float* __restrict__ pTm = (t > 0)      ? pT - sT : pT;
    const float* __restrict__ pTp = (t < TS - 1) ? pT + sT : pT;
    const float* __restrict__ pUm = (t > 0)      ? pU - sT : pU;
    const float* __restrict__ pUp = (t < TS - 1) ? pU + sT : pU;
    const float* __restrict__ pVm = (t > 0)      ? pV - sT : pV;
    const float* __restrict__ pVp = (t < TS - 1) ? pV + sT : pV;

    // z-ring warm-up (clamped rows; clamped values feed only edge branches)
    float4 Tzm2 = LD4(pT + ROW(z0 - 2) + x0), Tzm1 = LD4(pT + ROW(z0 - 1) + x0);
    float4 Tzc  = LD4(pT + ROW(z0)     + x0), Tzp1 = LD4(pT + ROW(z0 + 1) + x0);
    float4 Uzm2 = LD4(pU + ROW(z0 - 2) + x0), Uzm1 = LD4(pU + ROW(z0 - 1) + x0);
    float4 Uzc  = LD4(pU + ROW(z0)     + x0), Uzp1 = LD4(pU + ROW(z0 + 1) + x0);
    float4 Vzm2 = LD4(pV + ROW(z0 - 2) + x0), Vzm1 = LD4(pV + ROW(z0 - 1) + x0);
    float4 Vzc  = LD4(pV + ROW(z0)     + x0), Vzp1 = LD4(pV + ROW(z0 + 1) + x0);
    float4 a3 = LD4(q3 + ROW(z0 - 1) + x0), a4 = LD4(q4 + ROW(z0 - 1) + x0);
    float4 Pzm1 = make_float4(a3.x + a4.x, a3.y + a4.y, a3.z + a4.z, a3.w + a4.w);
    a3 = LD4(q3 + ROW(z0) + x0); a4 = LD4(q4 + ROW(z0) + x0);
    float4 Pzc  = make_float4(a3.x + a4.x, a3.y + a4.y, a3.z + a4.z, a3.w + a4.w);

    float acc = 0.f;

    for (int z = z0; z < z0 + ZS; ++z) {
        const int rC = z * WW;
        const int rzp2 = ROW(z + 2), rzp1 = ROW(z + 1);

        // issue ALL loads for this iteration up front
        float4 Tin = LD4(pT + rzp2 + x0);
        float4 Uin = LD4(pU + rzp2 + x0);
        float4 Vin = LD4(pV + rzp2 + x0);
        float4 b3  = LD4(q3 + rzp1 + x0);
        float4 b4  = LD4(q4 + rzp1 + x0);
        float4 Ttm = LD4(pTm + rC + x0), Ttp = LD4(pTp + rC + x0);
        float4 Utm = LD4(pUm + rC + x0), Utp = LD4(pUp + rC + x0);
        float4 Vtm = LD4(pVm + rC + x0), Vtp = LD4(pVp + rC + x0);

        // x-neighbors via intra-wave shuffles of the center quads
        float Tl2 = __shfl_up(Tzc.z, 1),   Tl3 = __shfl_up(Tzc.w, 1);
        float Tr0 = __shfl_down(Tzc.x, 1), Tr1 = __shfl_down(Tzc.y, 1);
        float Ul2 = __shfl_up(Uzc.z, 1),   Ul3 = __shfl_up(Uzc.w, 1);
        float Ur0 = __shfl_down(Uzc.x, 1), Ur1 = __shfl_down(Uzc.y, 1);
        float Vl2 = __shfl_up(Vzc.z, 1),   Vl3 = __shfl_up(Vzc.w, 1);
        float Vr0 = __shfl_down(Vzc.x, 1), Vr1 = __shfl_down(Vzc.y, 1);
        float Pl3 = __shfl_up(Pzc.w, 1),   Pr0 = __shfl_down(Pzc.x, 1);

        // wave-seam fixup (x=252..255 | 256..259 boundary between the 2 waves)
        if (threadIdx.x == 63) {
            float2 tv = *(const float2*)(pT + rC + 256); Tr0 = tv.x; Tr1 = tv.y;
            float2 uv = *(const float2*)(pU + rC + 256); Ur0 = uv.x; Ur1 = uv.y;
            float2 vv = *(const float2*)(pV + rC + 256); Vr0 = vv.x; Vr1 = vv.y;
            Pr0 = q3[rC + 256] + q4[rC + 256];
        } else if (threadIdx.x == 64) {
            float2 tv = *(const float2*)(pT + rC + 254); Tl2 = tv.x; Tl3 = tv.y;
            float2 uv = *(const float2*)(pU + rC + 254); Ul2 = uv.x; Ul3 = uv.y;
            float2 vv = *(const float2*)(pV + rC + 254); Vl2 = vv.x; Vl3 = vv.y;
            Pl3 = q3[rC + 255] + q4[rC + 255];
        }

        float4 Pin = make_float4(b3.x + b4.x, b3.y + b4.y, b3.z + b4.z, b3.w + b4.w);

        #pragma unroll
        for (int e = 0; e < 4; ++e) {
            const int i = x0 + e;
            const float txm2 = e == 0 ? Tl2 : e == 1 ? Tl3 : elem(Tzc, e - 2);
            const float txm1 = e == 0 ? Tl3 : elem(Tzc, e - 1);
            const float txc  = elem(Tzc, e);
            const float txp1 = e == 3 ? Tr0 : elem(Tzc, e + 1);
            const float txp2 = e == 2 ? Tr0 : e == 3 ? Tr1 : elem(Tzc, e + 2);
            const float uxm2 = e == 0 ? Ul2 : e == 1 ? Ul3 : elem(Uzc, e - 2);
            const float uxm1 = e == 0 ? Ul3 : elem(Uzc, e - 1);
            const float uxc  = elem(Uzc, e);
            const float uxp1 = e == 3 ? Ur0 : elem(Uzc, e + 1);
            const float uxp2 = e == 2 ? Ur0 : e == 3 ? Ur1 : elem(Uzc, e + 2);
            const float vxm2 = e == 0 ? Vl2 : e == 1 ? Vl3 : elem(Vzc, e - 2);
            const float vxm1 = e == 0 ? Vl3 : elem(Vzc, e - 1);
            const float vxc  = elem(Vzc, e);
            const float vxp1 = e == 3 ? Vr0 : elem(Vzc, e + 1);
            const float vxp2 = e == 2 ? Vr0 : e == 3 ? Vr1 : elem(Vzc, e + 2);
            const float pxm1 = e == 0 ? Pl3 : elem(Pzc, e - 1);
            const float pxc  = elem(Pzc, e);
            const float pxp1 = e == 3 ? Pr0 : elem(Pzc, e + 1);

            float dTdx, dTdxx, dTdz, dTdzz;
            grad12(txm2, txm1, txc, txp1, txp2, i, WW, invdx, dTdx, dTdxx);
            grad12(elem(Tzm2, e), elem(Tzm1, e), txc, elem(Tzp1, e), elem(Tin, e), z, HH, invdz, dTdz, dTdzz);
            float dUdx, dUdxx, dUdz, dUdzz;
            grad12(uxm2, uxm1, uxc, uxp1, uxp2, i, WW, invdx, dUdx, dUdxx);
            grad12(elem(Uzm2, e), elem(Uzm1, e), uxc, elem(Uzp1, e), elem(Uin, e), z, HH, invdz, dUdz, dUdzz);
            float dVdx, dVdxx, dVdz, dVdzz;
            grad12(vxm2, vxm1, vxc, vxp1, vxp2, i, WW, invdx, dVdx, dVdxx);
            grad12(elem(Vzm2, e), elem(Vzm1, e), vxc, elem(Vzp1, e), elem(Vin, e), z, HH, invdz, dVdz, dVdzz);

            float dPdx = grad1(pxm1, pxc, pxp1, i, WW, invdx);
            float dPdz = grad1(elem(Pzm1, e), pxc, elem(Pin, e), z, HH, invdz);

            float dTdt, dUdt, dVdt;   // t is block-uniform
            if (t == 0) {
                dTdt = (elem(Ttp, e) - txc) * invdt;
                dUdt = (elem(Utp, e) - uxc) * invdt;
                dVdt = (elem(Vtp, e) - vxc) * invdt;
            } else if (t == TS - 1) {
                dTdt = (txc - elem(Ttm, e)) * invdt;
                dUdt = (uxc - elem(Utm, e)) * invdt;
                dVdt = (vxc - elem(Vtm, e)) * invdt;
            } else {
                dTdt = (elem(Ttp, e) - elem(Ttm, e)) * (0.5f * invdt);
                dUdt = (elem(Utp, e) - elem(Utm, e)) * (0.5f * invdt);
                dVdt = (elem(Vtp, e) - elem(Vtm, e)) * (0.5f * invdt);
            }

            float div = dUdx + dVdz;
            float te  = dTdt + uxc * dTdx + vxc * dTdz - KAPPA * (dTdxx + dTdzz);
            float xm  = dUdt + uxc * dUdx + vxc * dUdz + dPdx - NU * (dUdxx + dUdzz);
            float zm  = dVdt + uxc * dVdx + vxc * dVdz + dPdz - NU * (dVdxx + dVdzz) - txc;

            acc += div * div + te * te + xm * xm + zm * zm;
        }

        // shift rings
        Tzm2 = Tzm1; Tzm1 = Tzc; Tzc = Tzp1; Tzp1 = Tin;
        Uzm2 = Uzm1; Uzm1 = Uzc; Uzc = Uzp1; Uzp1 = Uin;
        Vzm2 = Vzm1; Vzm1 = Vzc; Vzc = Vzp1; Vzp1 = Vin;
        Pzm1 = Pzc;  Pzc  = Pin;
    }

    // block reduction: wave shfl -> LDS -> one double atomic per block
    #pragma unroll
    for (int off = 32; off; off >>= 1) acc += __shfl_down(acc, off, 64);
    __shared__ float wsum[2];
    const int lane = threadIdx.x & 63, wid = threadIdx.x >> 6;
    if (lane == 0) wsum[wid] = acc;
    __syncthreads();
    if (threadIdx.x == 0) {
        atomicAdd(dacc, (double)(wsum[0] + wsum[1]));
    }
}

__global__ void rbc_finalize(const double* __restrict__ dacc, float* __restrict__ out) {
    const double N = (double)NB * TS * HH * WW;   // 12,582,912
    out[0] = (float)(dacc[0] / N);
}

extern "C" void kernel_launch(void* const* d_in, const int* in_sizes, int n_in,
                              void* d_out, int out_size, void* d_ws, size_t ws_size,
                              hipStream_t stream) {
    const float* pred = (const float*)d_in[0];
    double* dacc = (double*)d_ws;
    hipMemsetAsync(dacc, 0, sizeof(double), stream);

    const int nblocks = NB * TS * NSTRIP;   // 1536 blocks x 128 threads
    rbc_loss_kernel<<<nblocks, 128, 0, stream>>>(pred, dacc);
    rbc_finalize<<<1, 1, 0, stream>>>(dacc, (float*)d_out);
}